// Round 7
// baseline (373.392 us; speedup 1.0000x reference)
//
#include <hip/hip_runtime.h>
#include <hip/hip_bf16.h>

#define D  128
#define KN 32
#define LST 136   // LDS row stride (ushorts): 272 B = 17*16 B

typedef __attribute__((ext_vector_type(8))) short bf16x8;
typedef __attribute__((ext_vector_type(4))) float f32x4;

static __device__ __forceinline__ unsigned short f2bf(float f) {
    union { float f; unsigned int u; } v; v.f = f;
    unsigned int u = v.u;
    u += 0x7fff + ((u >> 16) & 1);   // RNE
    return (unsigned short)(u >> 16);
}
static __device__ __forceinline__ float bflo(unsigned int u) {
    union { float f; unsigned int u; } v; v.u = u << 16; return v.f;
}
static __device__ __forceinline__ float bfhi(unsigned int u) {
    union { float f; unsigned int u; } v; v.u = u & 0xffff0000u; return v.f;
}
static __device__ __forceinline__ unsigned int pk2bf(float a, float b) {
    float2 t; t.x = a; t.y = b;
    __hip_bfloat162 h = __float22bfloat162_rn(t);
    union { __hip_bfloat162 h; unsigned int u; } v; v.h = h;
    return v.u;
}

// One-shot: transpose+convert W1 halves and W2 into bf16 [col][k] layouts.
__global__ __launch_bounds__(256) void wt_kernel(
    const float* __restrict__ W1, const float* __restrict__ W2,
    unsigned short* __restrict__ W1Tt, unsigned short* __restrict__ W1Tb,
    unsigned short* __restrict__ W2T)
{
    int idx = blockIdx.x * 256 + threadIdx.x;
    if (idx < D * D) {
        int col = idx >> 7, e = idx & 127;
        W1Tt[col * D + e] = f2bf(W1[e * D + col]);
        W1Tb[col * D + e] = f2bf(W1[(D + e) * D + col]);
        W2T [col * D + e] = f2bf(W2[e * D + col]);
    }
}

// Q = emb[vnodes] @ W1bot + b1  (fp32 out; 20000 x 128)
__global__ __launch_bounds__(256) void q_kernel(
    const float* __restrict__ emb, const int* __restrict__ vnodes, int NN,
    const unsigned short* __restrict__ W1Tb, const float* __restrict__ b1,
    float* __restrict__ Qf)
{
    __shared__ unsigned short sA[128][LST];

    const int tid  = threadIdx.x;
    const int lane = tid & 63;
    const int w    = tid >> 6;
    const int m    = lane & 15, q = lane >> 4;
    const int r0   = blockIdx.x * 128;

#pragma unroll
    for (int i = 0; i < 16; ++i) {
        int e = tid + 256 * i;
        int row = e >> 5, c4 = (e & 31) << 2;
        int r = r0 + row; if (r > NN - 1) r = NN - 1;
        int vr = vnodes[r];
        const float4 f = *(const float4*)(emb + (long)vr * D + c4);
        ushort4 h;
        h.x = f2bf(f.x); h.y = f2bf(f.y); h.z = f2bf(f.z); h.w = f2bf(f.w);
        *(ushort4*)(&sA[row][c4]) = h;
    }
    __syncthreads();

    bf16x8 Bf[2][4];
#pragma unroll
    for (int nt = 0; nt < 2; ++nt)
#pragma unroll
        for (int kk = 0; kk < 4; ++kk)
            Bf[nt][kk] = *(const bf16x8*)(W1Tb + (32 * w + 16 * nt + m) * D + kk * 32 + q * 8);
    float bv[2];
#pragma unroll
    for (int nt = 0; nt < 2; ++nt) bv[nt] = b1[32 * w + 16 * nt + m];

    f32x4 acc[8][2];
#pragma unroll
    for (int mt = 0; mt < 8; ++mt)
#pragma unroll
        for (int nt = 0; nt < 2; ++nt) acc[mt][nt] = (f32x4){0.f, 0.f, 0.f, 0.f};

#pragma unroll
    for (int kk = 0; kk < 4; ++kk)
#pragma unroll
        for (int mt = 0; mt < 8; ++mt) {
            bf16x8 a = *(const bf16x8*)(&sA[16 * mt + m][kk * 32 + q * 8]);
            acc[mt][0] = __builtin_amdgcn_mfma_f32_16x16x32_bf16(a, Bf[0][kk], acc[mt][0], 0, 0, 0);
            acc[mt][1] = __builtin_amdgcn_mfma_f32_16x16x32_bf16(a, Bf[1][kk], acc[mt][1], 0, 0, 0);
        }

#pragma unroll
    for (int mt = 0; mt < 8; ++mt)
#pragma unroll
        for (int nt = 0; nt < 2; ++nt) {
            int col = 32 * w + 16 * nt + m;
#pragma unroll
            for (int r = 0; r < 4; ++r) {
                int row = r0 + 16 * mt + 4 * q + r;
                if (row < NN) Qf[(long)row * D + col] = acc[mt][nt][r] + bv[nt];
            }
        }
}

// Fully-fused aggregator, 2 nodes/group, separate sEg/sX buffers (no spills).
// stage(gather fp32 emb -> bf16 sEg, Qf -> sQf) ; B1
// layer-1 MFMA (A=W1T regs, B=sEg rows) -> X=relu(+Qf) into sX ; B3
// layer-2 MFMA (A=sX, B=W2T regs) -> scores ; B4 ; softmax ; B5
// aggregation from sEg+sAtt ; B6.
__global__ __launch_bounds__(256, 3) void agg_kernel(
    const float* __restrict__ emb, const int* __restrict__ nidx,
    const unsigned short* __restrict__ W1Tt, const unsigned short* __restrict__ W2T,
    const float* __restrict__ b2, const float* __restrict__ W3,
    const float* __restrict__ Qf,
    float* __restrict__ out, int NN)
{
    __shared__ unsigned short sEg[64][LST];   // gathered emb rows (bf16)
    __shared__ unsigned short sX[64][LST];    // layer-1 output
    __shared__ float sQf[2][D];
    __shared__ float sSp[4][64];
    __shared__ float sAtt[64];

    const int tid  = threadIdx.x;
    const int lane = tid & 63;
    const int w    = tid >> 6;
    const int m    = lane & 15, q = lane >> 4;

    // persistent fragments: W1T (layer-1 A, this wave's 32 X-cols),
    // W2T (layer-2 B, this wave's 32 H-cols)
    bf16x8 Af[2][4], Bf[2][4];
#pragma unroll
    for (int t = 0; t < 2; ++t)
#pragma unroll
        for (int kk = 0; kk < 4; ++kk) {
            Af[t][kk] = *(const bf16x8*)(W1Tt + (32 * w + 16 * t + m) * D + kk * 32 + q * 8);
            Bf[t][kk] = *(const bf16x8*)(W2T  + (32 * w + 16 * t + m) * D + kk * 32 + q * 8);
        }
    float b2v[2], w3v[2];
#pragma unroll
    for (int nt = 0; nt < 2; ++nt) {
        int col = 32 * w + 16 * nt + m;
        b2v[nt] = b2[col];
        w3v[nt] = W3[col];
    }

    const int groups = (NN + 1) >> 1;
    for (int g = blockIdx.x; g < groups; g += gridDim.x) {
        const int node0 = g * 2;

        // ---- stage sQf: 256 threads x 1 float ----
        {
            int nd = tid >> 7, c = tid & 127;
            int ndg = node0 + nd; if (ndg > NN - 1) ndg = NN - 1;
            sQf[nd][c] = Qf[(long)ndg * D + c];
        }
        // ---- stage sEg: 4 threads/row, fp32 gather -> bf16 ----
        {
            int row = tid >> 2, qt = tid & 3;
            int ndg = node0 + (row >> 5); if (ndg > NN - 1) ndg = NN - 1;
            int ni = nidx[ndg * KN + (row & 31)];
            const float* src = emb + (long)ni * D + qt * 32;
            float4 f0 = *(const float4*)(src);
            float4 f1 = *(const float4*)(src + 4);
            float4 f2 = *(const float4*)(src + 8);
            float4 f3 = *(const float4*)(src + 12);
            float4 f4 = *(const float4*)(src + 16);
            float4 f5 = *(const float4*)(src + 20);
            float4 f6 = *(const float4*)(src + 24);
            float4 f7 = *(const float4*)(src + 28);
            uint4 p0, p1;
            p0.x = pk2bf(f0.x, f0.y); p0.y = pk2bf(f0.z, f0.w);
            p0.z = pk2bf(f1.x, f1.y); p0.w = pk2bf(f1.z, f1.w);
            p1.x = pk2bf(f2.x, f2.y); p1.y = pk2bf(f2.z, f2.w);
            p1.z = pk2bf(f3.x, f3.y); p1.w = pk2bf(f3.z, f3.w);
            *(uint4*)(&sEg[row][qt * 32])     = p0;
            *(uint4*)(&sEg[row][qt * 32 + 8]) = p1;
            uint4 p2, p3;
            p2.x = pk2bf(f4.x, f4.y); p2.y = pk2bf(f4.z, f4.w);
            p2.z = pk2bf(f5.x, f5.y); p2.w = pk2bf(f5.z, f5.w);
            p3.x = pk2bf(f6.x, f6.y); p3.y = pk2bf(f6.z, f6.w);
            p3.z = pk2bf(f7.x, f7.y); p3.w = pk2bf(f7.z, f7.w);
            *(uint4*)(&sEg[row][qt * 32 + 16]) = p2;
            *(uint4*)(&sEg[row][qt * 32 + 24]) = p3;
        }
        __syncthreads();   // B1: sEg, sQf ready

        // ---- layer-1: D[Xcol][row] = W1T @ Eg^T (this wave's 32 X-cols) ----
        {
            f32x4 acc1[2][4];
#pragma unroll
            for (int t = 0; t < 2; ++t)
#pragma unroll
                for (int nt = 0; nt < 4; ++nt) acc1[t][nt] = (f32x4){0.f, 0.f, 0.f, 0.f};

#pragma unroll
            for (int kk = 0; kk < 4; ++kk)
#pragma unroll
                for (int nt = 0; nt < 4; ++nt) {
                    bf16x8 e = *(const bf16x8*)(&sEg[16 * nt + m][kk * 32 + q * 8]);
                    acc1[0][nt] = __builtin_amdgcn_mfma_f32_16x16x32_bf16(Af[0][kk], e, acc1[0][nt], 0, 0, 0);
                    acc1[1][nt] = __builtin_amdgcn_mfma_f32_16x16x32_bf16(Af[1][kk], e, acc1[1][nt], 0, 0, 0);
                }

            // X = relu(acc1 + Qf) -> sX ; D-layout: col(lane&15)=row n, row-field=X-col
#pragma unroll
            for (int t = 0; t < 2; ++t) {
                int xc = 32 * w + 16 * t + 4 * q;
                float q0[4];
#pragma unroll
                for (int nt = 0; nt < 4; ++nt) {
                    int n = 16 * nt + m;           // neighbor row 0..63
                    int nd = n >> 5;
                    float v0 = fmaxf(acc1[t][nt][0] + sQf[nd][xc],     0.f);
                    float v1 = fmaxf(acc1[t][nt][1] + sQf[nd][xc + 1], 0.f);
                    float v2 = fmaxf(acc1[t][nt][2] + sQf[nd][xc + 2], 0.f);
                    float v3 = fmaxf(acc1[t][nt][3] + sQf[nd][xc + 3], 0.f);
                    uint2 pk; pk.x = pk2bf(v0, v1); pk.y = pk2bf(v2, v3);
                    *(uint2*)(&sX[n][xc]) = pk;
                }
                (void)q0;
            }
        }
        __syncthreads();   // B3: sX ready

        // ---- layer-2: H = X @ W2 (this wave's 32 H-cols) + scores ----
        {
            f32x4 acc[4][2];
#pragma unroll
            for (int mt = 0; mt < 4; ++mt)
#pragma unroll
                for (int nt = 0; nt < 2; ++nt) acc[mt][nt] = (f32x4){0.f, 0.f, 0.f, 0.f};

#pragma unroll
            for (int kk = 0; kk < 4; ++kk)
#pragma unroll
                for (int mt = 0; mt < 4; ++mt) {
                    bf16x8 a = *(const bf16x8*)(&sX[16 * mt + m][kk * 32 + q * 8]);
                    acc[mt][0] = __builtin_amdgcn_mfma_f32_16x16x32_bf16(a, Bf[0][kk], acc[mt][0], 0, 0, 0);
                    acc[mt][1] = __builtin_amdgcn_mfma_f32_16x16x32_bf16(a, Bf[1][kk], acc[mt][1], 0, 0, 0);
                }

#pragma unroll
            for (int mt = 0; mt < 4; ++mt) {
                float p[4];
#pragma unroll
                for (int r = 0; r < 4; ++r) {
                    float h0 = acc[mt][0][r] + b2v[0]; h0 = h0 > 0.f ? h0 : 0.f;
                    float h1 = acc[mt][1][r] + b2v[1]; h1 = h1 > 0.f ? h1 : 0.f;
                    p[r] = h0 * w3v[0] + h1 * w3v[1];
                }
#pragma unroll
                for (int off = 8; off >= 1; off >>= 1)
#pragma unroll
                    for (int r = 0; r < 4; ++r) p[r] += __shfl_xor(p[r], off, 16);
                if (m == 0) {
#pragma unroll
                    for (int r = 0; r < 4; ++r) sSp[w][16 * mt + 4 * q + r] = p[r];
                }
            }
        }
        __syncthreads();   // B4: sSp ready

        // ---- softmax: 64 scores = 2 nodes x 32 (b3 cancels) ----
        if (tid < 64) {
            float s = sSp[0][tid] + sSp[1][tid] + sSp[2][tid] + sSp[3][tid];
            float mx = s;
#pragma unroll
            for (int off = 16; off >= 1; off >>= 1) mx = fmaxf(mx, __shfl_xor(mx, off, 32));
            float e = __expf(s - mx);
            float sum = e;
#pragma unroll
            for (int off = 16; off >= 1; off >>= 1) sum += __shfl_xor(sum, off, 32);
            sAtt[tid] = e / sum;
        }
        __syncthreads();   // B5: sAtt ready

        // ---- aggregation: 128 threads = 2 nodes x 64 col-pairs ----
        if (tid < 128) {
            int nd = tid >> 6, c2 = tid & 63;
            float ox = 0.f, oy = 0.f;
#pragma unroll
            for (int k = 0; k < KN; ++k) {
                float a = sAtt[nd * KN + k];
                unsigned int v = *(const unsigned int*)(&sEg[nd * KN + k][c2 * 2]);
                ox += a * bflo(v);
                oy += a * bfhi(v);
            }
            int ndg = node0 + nd;
            if (ndg < NN) {
                float2 o = {ox, oy};
                *(float2*)(out + (long)ndg * D + c2 * 2) = o;
            }
        }
        __syncthreads();   // B6: protect sEg/sQf/sSp/sAtt for next iteration
    }
}

// Correct-but-slow fp32 VALU fallback (only if ws is too small).
__global__ __launch_bounds__(128) void naive_kernel(
    const float* __restrict__ emb, const int* __restrict__ vnodes,
    const int* __restrict__ nidx,
    const float* __restrict__ W1, const float* __restrict__ b1,
    const float* __restrict__ W2, const float* __restrict__ b2,
    const float* __restrict__ W3, const float* __restrict__ b3,
    float* __restrict__ out)
{
    __shared__ float sE[KN + 1][D];
    __shared__ float sH[KN][D];
    __shared__ float sH2[KN][D];
    __shared__ float sS[KN];
    __shared__ float sA2[KN];
    const int node = blockIdx.x, tid = threadIdx.x;

    for (int r = 0; r < KN + 1; ++r) {
        int vr = (r < KN) ? nidx[node * KN + r] : vnodes[node];
        sE[r][tid] = emb[(long)vr * D + tid];
    }
    __syncthreads();
    for (int k = 0; k < KN; ++k) {
        float s = b1[tid];
        for (int e = 0; e < D; ++e) s += sE[k][e]  * W1[e * D + tid];
        for (int e = 0; e < D; ++e) s += sE[KN][e] * W1[(D + e) * D + tid];
        sH[k][tid] = s > 0.f ? s : 0.f;
    }
    __syncthreads();
    for (int k = 0; k < KN; ++k) {
        float s = b2[tid];
        for (int e = 0; e < D; ++e) s += sH[k][e] * W2[e * D + tid];
        sH2[k][tid] = s > 0.f ? s : 0.f;
    }
    __syncthreads();
    if (tid < KN) {
        float s = b3[0];
        for (int e = 0; e < D; ++e) s += sH2[tid][e] * W3[e];
        sS[tid] = s;
    }
    __syncthreads();
    if (tid == 0) {
        float mx = sS[0];
        for (int k = 1; k < KN; ++k) mx = fmaxf(mx, sS[k]);
        float sum = 0.f;
        for (int k = 0; k < KN; ++k) { sA2[k] = __expf(sS[k] - mx); sum += sA2[k]; }
        for (int k = 0; k < KN; ++k) sA2[k] /= sum;
    }
    __syncthreads();
    float a = 0.f;
    for (int k = 0; k < KN; ++k) a += sA2[k] * sE[k][tid];
    out[(long)node * D + tid] = a;
}

extern "C" void kernel_launch(void* const* d_in, const int* in_sizes, int n_in,
                              void* d_out, int out_size, void* d_ws, size_t ws_size,
                              hipStream_t stream) {
    const float* emb    = (const float*)d_in[0];
    const int*   vnodes = (const int*)d_in[1];
    const int*   nidx   = (const int*)d_in[2];
    const float* W1     = (const float*)d_in[3];
    const float* b1     = (const float*)d_in[4];
    const float* W2     = (const float*)d_in[5];
    const float* b2     = (const float*)d_in[6];
    const float* W3     = (const float*)d_in[7];
    const float* b3     = (const float*)d_in[8];
    float* out = (float*)d_out;

    const int NN = in_sizes[1];       // 20000

    const size_t q_bytes  = (size_t)NN * D * sizeof(float);
    const size_t wt_elems = (size_t)D * D;
    const size_t need = q_bytes + 3 * wt_elems * sizeof(unsigned short);

    if (ws_size >= need) {
        float* Qf            = (float*)d_ws;
        unsigned short* W1Tt = (unsigned short*)((char*)d_ws + q_bytes);
        unsigned short* W1Tb = W1Tt + wt_elems;
        unsigned short* W2T  = W1Tb + wt_elems;

        wt_kernel<<<(D * D + 255) / 256, 256, 0, stream>>>(W1, W2, W1Tt, W1Tb, W2T);
        q_kernel<<<(NN + 127) / 128, 256, 0, stream>>>(emb, vnodes, NN, W1Tb, b1, Qf);
        agg_kernel<<<4096, 256, 0, stream>>>(
            emb, nidx, W1Tt, W2T, b2, W3, Qf, out, NN);
    } else {
        naive_kernel<<<NN, D, 0, stream>>>(emb, vnodes, nidx, W1, b1, W2, b2, W3, b3, out);
    }
}

// Round 8
// 314.460 us; speedup vs baseline: 1.1874x; 1.1874x over previous
//
#include <hip/hip_runtime.h>
#include <hip/hip_bf16.h>

#define D  128
#define KN 32
#define LST 136   // LDS row stride (ushorts): 272 B = 17*16 B

typedef __attribute__((ext_vector_type(8))) short bf16x8;
typedef __attribute__((ext_vector_type(4))) float f32x4;

static __device__ __forceinline__ unsigned short f2bf(float f) {
    union { float f; unsigned int u; } v; v.f = f;
    unsigned int u = v.u;
    u += 0x7fff + ((u >> 16) & 1);   // RNE
    return (unsigned short)(u >> 16);
}
static __device__ __forceinline__ float bflo(unsigned int u) {
    union { float f; unsigned int u; } v; v.u = u << 16; return v.f;
}
static __device__ __forceinline__ float bfhi(unsigned int u) {
    union { float f; unsigned int u; } v; v.u = u & 0xffff0000u; return v.f;
}
static __device__ __forceinline__ unsigned int pk2bf(float a, float b) {
    float2 t; t.x = a; t.y = b;
    __hip_bfloat162 h = __float22bfloat162_rn(t);
    union { __hip_bfloat162 h; unsigned int u; } v; v.h = h;
    return v.u;
}

// One-shot: transpose+convert W1 halves and W2 into bf16 [col][k] layouts.
__global__ __launch_bounds__(256) void wt_kernel(
    const float* __restrict__ W1, const float* __restrict__ W2,
    unsigned short* __restrict__ W1Tt, unsigned short* __restrict__ W1Tb,
    unsigned short* __restrict__ W2T)
{
    int idx = blockIdx.x * 256 + threadIdx.x;
    if (idx < D * D) {
        int col = idx >> 7, e = idx & 127;
        W1Tt[col * D + e] = f2bf(W1[e * D + col]);
        W1Tb[col * D + e] = f2bf(W1[(D + e) * D + col]);
        W2T [col * D + e] = f2bf(W2[e * D + col]);
    }
}

// Q = emb[vnodes] @ W1bot + b1  (fp32 out; 20000 x 128)
__global__ __launch_bounds__(256) void q_kernel(
    const float* __restrict__ emb, const int* __restrict__ vnodes, int NN,
    const unsigned short* __restrict__ W1Tb, const float* __restrict__ b1,
    float* __restrict__ Qf)
{
    __shared__ unsigned short sA[128][LST];

    const int tid  = threadIdx.x;
    const int lane = tid & 63;
    const int w    = tid >> 6;
    const int m    = lane & 15, q = lane >> 4;
    const int r0   = blockIdx.x * 128;

#pragma unroll
    for (int i = 0; i < 16; ++i) {
        int e = tid + 256 * i;
        int row = e >> 5, c4 = (e & 31) << 2;
        int r = r0 + row; if (r > NN - 1) r = NN - 1;
        int vr = vnodes[r];
        const float4 f = *(const float4*)(emb + (long)vr * D + c4);
        ushort4 h;
        h.x = f2bf(f.x); h.y = f2bf(f.y); h.z = f2bf(f.z); h.w = f2bf(f.w);
        *(ushort4*)(&sA[row][c4]) = h;
    }
    __syncthreads();

    bf16x8 Bf[2][4];
#pragma unroll
    for (int nt = 0; nt < 2; ++nt)
#pragma unroll
        for (int kk = 0; kk < 4; ++kk)
            Bf[nt][kk] = *(const bf16x8*)(W1Tb + (32 * w + 16 * nt + m) * D + kk * 32 + q * 8);
    float bv[2];
#pragma unroll
    for (int nt = 0; nt < 2; ++nt) bv[nt] = b1[32 * w + 16 * nt + m];

    f32x4 acc[8][2];
#pragma unroll
    for (int mt = 0; mt < 8; ++mt)
#pragma unroll
        for (int nt = 0; nt < 2; ++nt) acc[mt][nt] = (f32x4){0.f, 0.f, 0.f, 0.f};

#pragma unroll
    for (int kk = 0; kk < 4; ++kk)
#pragma unroll
        for (int mt = 0; mt < 8; ++mt) {
            bf16x8 a = *(const bf16x8*)(&sA[16 * mt + m][kk * 32 + q * 8]);
            acc[mt][0] = __builtin_amdgcn_mfma_f32_16x16x32_bf16(a, Bf[0][kk], acc[mt][0], 0, 0, 0);
            acc[mt][1] = __builtin_amdgcn_mfma_f32_16x16x32_bf16(a, Bf[1][kk], acc[mt][1], 0, 0, 0);
        }

#pragma unroll
    for (int mt = 0; mt < 8; ++mt)
#pragma unroll
        for (int nt = 0; nt < 2; ++nt) {
            int col = 32 * w + 16 * nt + m;
#pragma unroll
            for (int r = 0; r < 4; ++r) {
                int row = r0 + 16 * mt + 4 * q + r;
                if (row < NN) Qf[(long)row * D + col] = acc[mt][nt][r] + bv[nt];
            }
        }
}

// Fully-fused aggregator: one block = 2 nodes, no loop, no launch-bound cap.
// stage(gather fp32 emb -> bf16 sEg, Qf -> sQf) ; B1
// layer-1 MFMA (A=W1T per-kk frags, B=sEg rows) -> X=relu(+Qf) into sX ; B2
// layer-2 MFMA (A=sX, B=W2T per-kk frags) -> scores ; B3 ; softmax ; B4
// aggregation from sEg+sAtt -> out.
__global__ __launch_bounds__(256) void agg_kernel(
    const float* __restrict__ emb, const int* __restrict__ nidx,
    const unsigned short* __restrict__ W1Tt, const unsigned short* __restrict__ W2T,
    const float* __restrict__ b2, const float* __restrict__ W3,
    const float* __restrict__ Qf,
    float* __restrict__ out, int NN)
{
    __shared__ unsigned short sEg[64][LST];   // gathered emb rows (bf16)
    __shared__ unsigned short sX[64][LST];    // layer-1 output
    __shared__ float sQf[2][D];
    __shared__ float sSp[4][64];
    __shared__ float sAtt[64];

    const int tid  = threadIdx.x;
    const int lane = tid & 63;
    const int w    = tid >> 6;
    const int m    = lane & 15, q = lane >> 4;
    const int node0 = blockIdx.x * 2;

    // ---- stage sQf: 256 threads x 1 float ----
    {
        int nd = tid >> 7, c = tid & 127;
        int ndg = node0 + nd; if (ndg > NN - 1) ndg = NN - 1;
        sQf[nd][c] = Qf[(long)ndg * D + c];
    }
    // ---- stage sEg: 4 threads/row, fp32 gather -> bf16 ----
    {
        int row = tid >> 2, qt = tid & 3;
        int ndg = node0 + (row >> 5); if (ndg > NN - 1) ndg = NN - 1;
        int ni = nidx[ndg * KN + (row & 31)];
        const float* src = emb + (long)ni * D + qt * 32;
        float4 f0 = *(const float4*)(src);
        float4 f1 = *(const float4*)(src + 4);
        float4 f2 = *(const float4*)(src + 8);
        float4 f3 = *(const float4*)(src + 12);
        uint4 p0, p1;
        p0.x = pk2bf(f0.x, f0.y); p0.y = pk2bf(f0.z, f0.w);
        p0.z = pk2bf(f1.x, f1.y); p0.w = pk2bf(f1.z, f1.w);
        p1.x = pk2bf(f2.x, f2.y); p1.y = pk2bf(f2.z, f2.w);
        p1.z = pk2bf(f3.x, f3.y); p1.w = pk2bf(f3.z, f3.w);
        *(uint4*)(&sEg[row][qt * 32])     = p0;
        *(uint4*)(&sEg[row][qt * 32 + 8]) = p1;
        float4 f4 = *(const float4*)(src + 16);
        float4 f5 = *(const float4*)(src + 20);
        float4 f6 = *(const float4*)(src + 24);
        float4 f7 = *(const float4*)(src + 28);
        uint4 p2, p3;
        p2.x = pk2bf(f4.x, f4.y); p2.y = pk2bf(f4.z, f4.w);
        p2.z = pk2bf(f5.x, f5.y); p2.w = pk2bf(f5.z, f5.w);
        p3.x = pk2bf(f6.x, f6.y); p3.y = pk2bf(f6.z, f6.w);
        p3.z = pk2bf(f7.x, f7.y); p3.w = pk2bf(f7.z, f7.w);
        *(uint4*)(&sEg[row][qt * 32 + 16]) = p2;
        *(uint4*)(&sEg[row][qt * 32 + 24]) = p3;
    }
    __syncthreads();   // B1: sEg, sQf ready

    // ---- layer-1: W1T @ Eg^T (this wave's 32 X-cols), frags per-kk ----
    {
        f32x4 acc1[2][4];
#pragma unroll
        for (int t = 0; t < 2; ++t)
#pragma unroll
            for (int nt = 0; nt < 4; ++nt) acc1[t][nt] = (f32x4){0.f, 0.f, 0.f, 0.f};

#pragma unroll
        for (int kk = 0; kk < 4; ++kk) {
            bf16x8 A0 = *(const bf16x8*)(W1Tt + (32 * w + m) * D + kk * 32 + q * 8);
            bf16x8 A1 = *(const bf16x8*)(W1Tt + (32 * w + 16 + m) * D + kk * 32 + q * 8);
#pragma unroll
            for (int nt = 0; nt < 4; ++nt) {
                bf16x8 e = *(const bf16x8*)(&sEg[16 * nt + m][kk * 32 + q * 8]);
                acc1[0][nt] = __builtin_amdgcn_mfma_f32_16x16x32_bf16(A0, e, acc1[0][nt], 0, 0, 0);
                acc1[1][nt] = __builtin_amdgcn_mfma_f32_16x16x32_bf16(A1, e, acc1[1][nt], 0, 0, 0);
            }
        }

        // X = relu(acc1 + Qf) -> sX ; D-layout: col(lane&15)=neighbor, row=X-col
#pragma unroll
        for (int t = 0; t < 2; ++t) {
            int xc = 32 * w + 16 * t + 4 * q;
#pragma unroll
            for (int nt = 0; nt < 4; ++nt) {
                int n = 16 * nt + m;           // neighbor row 0..63
                int nd = n >> 5;
                float v0 = fmaxf(acc1[t][nt][0] + sQf[nd][xc],     0.f);
                float v1 = fmaxf(acc1[t][nt][1] + sQf[nd][xc + 1], 0.f);
                float v2 = fmaxf(acc1[t][nt][2] + sQf[nd][xc + 2], 0.f);
                float v3 = fmaxf(acc1[t][nt][3] + sQf[nd][xc + 3], 0.f);
                uint2 pk; pk.x = pk2bf(v0, v1); pk.y = pk2bf(v2, v3);
                *(uint2*)(&sX[n][xc]) = pk;
            }
        }
    }
    __syncthreads();   // B2: sX ready

    // ---- layer-2: H = X @ W2 (this wave's 32 H-cols) + scores ----
    {
        f32x4 acc[4][2];
#pragma unroll
        for (int mt = 0; mt < 4; ++mt)
#pragma unroll
            for (int nt = 0; nt < 2; ++nt) acc[mt][nt] = (f32x4){0.f, 0.f, 0.f, 0.f};

#pragma unroll
        for (int kk = 0; kk < 4; ++kk) {
            bf16x8 B0 = *(const bf16x8*)(W2T + (32 * w + m) * D + kk * 32 + q * 8);
            bf16x8 B1 = *(const bf16x8*)(W2T + (32 * w + 16 + m) * D + kk * 32 + q * 8);
#pragma unroll
            for (int mt = 0; mt < 4; ++mt) {
                bf16x8 a = *(const bf16x8*)(&sX[16 * mt + m][kk * 32 + q * 8]);
                acc[mt][0] = __builtin_amdgcn_mfma_f32_16x16x32_bf16(a, B0, acc[mt][0], 0, 0, 0);
                acc[mt][1] = __builtin_amdgcn_mfma_f32_16x16x32_bf16(a, B1, acc[mt][1], 0, 0, 0);
            }
        }

        const float b2v0 = b2[32 * w + m],      b2v1 = b2[32 * w + 16 + m];
        const float w3v0 = W3[32 * w + m],      w3v1 = W3[32 * w + 16 + m];
#pragma unroll
        for (int mt = 0; mt < 4; ++mt) {
            float p[4];
#pragma unroll
            for (int r = 0; r < 4; ++r) {
                float h0 = acc[mt][0][r] + b2v0; h0 = h0 > 0.f ? h0 : 0.f;
                float h1 = acc[mt][1][r] + b2v1; h1 = h1 > 0.f ? h1 : 0.f;
                p[r] = h0 * w3v0 + h1 * w3v1;
            }
#pragma unroll
            for (int off = 8; off >= 1; off >>= 1)
#pragma unroll
                for (int r = 0; r < 4; ++r) p[r] += __shfl_xor(p[r], off, 16);
            if (m == 0) {
#pragma unroll
                for (int r = 0; r < 4; ++r) sSp[w][16 * mt + 4 * q + r] = p[r];
            }
        }
    }
    __syncthreads();   // B3: sSp ready

    // ---- softmax: 64 scores = 2 nodes x 32 (b3 cancels) ----
    if (tid < 64) {
        float s = sSp[0][tid] + sSp[1][tid] + sSp[2][tid] + sSp[3][tid];
        float mx = s;
#pragma unroll
        for (int off = 16; off >= 1; off >>= 1) mx = fmaxf(mx, __shfl_xor(mx, off, 32));
        float e = __expf(s - mx);
        float sum = e;
#pragma unroll
        for (int off = 16; off >= 1; off >>= 1) sum += __shfl_xor(sum, off, 32);
        sAtt[tid] = e / sum;
    }
    __syncthreads();   // B4: sAtt ready

    // ---- aggregation: 128 threads = 2 nodes x 64 col-pairs ----
    if (tid < 128) {
        int nd = tid >> 6, c2 = tid & 63;
        float ox = 0.f, oy = 0.f;
#pragma unroll
        for (int k = 0; k < KN; ++k) {
            float a = sAtt[nd * KN + k];
            unsigned int v = *(const unsigned int*)(&sEg[nd * KN + k][c2 * 2]);
            ox += a * bflo(v);
            oy += a * bfhi(v);
        }
        int ndg = node0 + nd;
        if (ndg < NN) {
            float2 o = {ox, oy};
            *(float2*)(out + (long)ndg * D + c2 * 2) = o;
        }
    }
}

// Correct-but-slow fp32 VALU fallback (only if ws is too small).
__global__ __launch_bounds__(128) void naive_kernel(
    const float* __restrict__ emb, const int* __restrict__ vnodes,
    const int* __restrict__ nidx,
    const float* __restrict__ W1, const float* __restrict__ b1,
    const float* __restrict__ W2, const float* __restrict__ b2,
    const float* __restrict__ W3, const float* __restrict__ b3,
    float* __restrict__ out)
{
    __shared__ float sE[KN + 1][D];
    __shared__ float sH[KN][D];
    __shared__ float sH2[KN][D];
    __shared__ float sS[KN];
    __shared__ float sA2[KN];
    const int node = blockIdx.x, tid = threadIdx.x;

    for (int r = 0; r < KN + 1; ++r) {
        int vr = (r < KN) ? nidx[node * KN + r] : vnodes[node];
        sE[r][tid] = emb[(long)vr * D + tid];
    }
    __syncthreads();
    for (int k = 0; k < KN; ++k) {
        float s = b1[tid];
        for (int e = 0; e < D; ++e) s += sE[k][e]  * W1[e * D + tid];
        for (int e = 0; e < D; ++e) s += sE[KN][e] * W1[(D + e) * D + tid];
        sH[k][tid] = s > 0.f ? s : 0.f;
    }
    __syncthreads();
    for (int k = 0; k < KN; ++k) {
        float s = b2[tid];
        for (int e = 0; e < D; ++e) s += sH[k][e] * W2[e * D + tid];
        sH2[k][tid] = s > 0.f ? s : 0.f;
    }
    __syncthreads();
    if (tid < KN) {
        float s = b3[0];
        for (int e = 0; e < D; ++e) s += sH2[tid][e] * W3[e];
        sS[tid] = s;
    }
    __syncthreads();
    if (tid == 0) {
        float mx = sS[0];
        for (int k = 1; k < KN; ++k) mx = fmaxf(mx, sS[k]);
        float sum = 0.f;
        for (int k = 0; k < KN; ++k) { sA2[k] = __expf(sS[k] - mx); sum += sA2[k]; }
        for (int k = 0; k < KN; ++k) sA2[k] /= sum;
    }
    __syncthreads();
    float a = 0.f;
    for (int k = 0; k < KN; ++k) a += sA2[k] * sE[k][tid];
    out[(long)node * D + tid] = a;
}

extern "C" void kernel_launch(void* const* d_in, const int* in_sizes, int n_in,
                              void* d_out, int out_size, void* d_ws, size_t ws_size,
                              hipStream_t stream) {
    const float* emb    = (const float*)d_in[0];
    const int*   vnodes = (const int*)d_in[1];
    const int*   nidx   = (const int*)d_in[2];
    const float* W1     = (const float*)d_in[3];
    const float* b1     = (const float*)d_in[4];
    const float* W2     = (const float*)d_in[5];
    const float* b2     = (const float*)d_in[6];
    const float* W3     = (const float*)d_in[7];
    const float* b3     = (const float*)d_in[8];
    float* out = (float*)d_out;

    const int NN = in_sizes[1];       // 20000

    const size_t q_bytes  = (size_t)NN * D * sizeof(float);
    const size_t wt_elems = (size_t)D * D;
    const size_t need = q_bytes + 3 * wt_elems * sizeof(unsigned short);

    if (ws_size >= need) {
        float* Qf            = (float*)d_ws;
        unsigned short* W1Tt = (unsigned short*)((char*)d_ws + q_bytes);
        unsigned short* W1Tb = W1Tt + wt_elems;
        unsigned short* W2T  = W1Tb + wt_elems;

        wt_kernel<<<(D * D + 255) / 256, 256, 0, stream>>>(W1, W2, W1Tt, W1Tb, W2T);
        q_kernel<<<(NN + 127) / 128, 256, 0, stream>>>(emb, vnodes, NN, W1Tb, b1, Qf);
        agg_kernel<<<(NN + 1) / 2, 256, 0, stream>>>(
            emb, nidx, W1Tt, W2T, b2, W3, Qf, out, NN);
    } else {
        naive_kernel<<<NN, D, 0, stream>>>(emb, vnodes, nidx, W1, b1, W2, b2, W3, b3, out);
    }
}